// Round 2
// baseline (2150.752 us; speedup 1.0000x reference)
//
#include <hip/hip_runtime.h>
#include <math.h>

#define BB 8
#define CC 32
#define TT 9
#define LL 512
#define HH 8
#define DD 4
#define NBT (BB*TT)          // 72
#define RELN (2*LL-1)        // 1023

// ---------------- mixed bias: mb[Ho][idx] = sum_h rpb[h][idx] * Wl[h][Ho] ----------------
__global__ void mixed_bias_kernel(const float* __restrict__ rpb,
                                  const float* __restrict__ Wl,
                                  float* __restrict__ mb) {
  int idx = blockIdx.x * blockDim.x + threadIdx.x;
  if (idx >= RELN) return;
  float r[HH];
  #pragma unroll
  for (int h = 0; h < HH; ++h) r[h] = rpb[h*RELN + idx];
  #pragma unroll
  for (int Ho = 0; Ho < HH; ++Ho) {
    float acc = 0.f;
    #pragma unroll
    for (int h = 0; h < HH; ++h) acc += r[h] * Wl[h*HH + Ho];
    mb[Ho*RELN + idx] = acc;
  }
}

// ---------------- transpose pl_w (512x512): outT[l][l'] = in[l'][l] ----------------
__global__ __launch_bounds__(256) void transpose512_kernel(const float* __restrict__ in,
                                                           float* __restrict__ outT) {
  __shared__ float tile[32][33];
  int bx = blockIdx.x * 32, by = blockIdx.y * 32;
  int tx = threadIdx.x & 31, ty = threadIdx.x >> 5;   // 32x8
  #pragma unroll
  for (int yy = ty; yy < 32; yy += 8)
    tile[yy][tx] = in[(by + yy)*LL + bx + tx];
  __syncthreads();
  #pragma unroll
  for (int yy = ty; yy < 32; yy += 8)
    outT[(bx + yy)*LL + by + tx] = tile[tx][yy];
}

// ---------------- q/k/v projection + l2norm (q additionally scaled by 1/sqrt(D)=0.5) ----
// out layout: dst[(bt*HH + h)*(LL*DD) + l*DD + d]
__global__ __launch_bounds__(256) void proj_kernel(
    const float* __restrict__ x,
    const float* __restrict__ Wq, const float* __restrict__ bq,
    const float* __restrict__ Wk, const float* __restrict__ bk,
    const float* __restrict__ Wv, const float* __restrict__ bv,
    float* __restrict__ qo, float* __restrict__ ko, float* __restrict__ vo) {
  int g = blockIdx.x * 256 + threadIdx.x;    // 0..36863
  int l  = g & (LL-1);
  int bt = g >> 9;
  int b = bt / TT, t = bt - b*TT;

  float xv[CC];
  #pragma unroll
  for (int c = 0; c < CC; ++c)
    xv[c] = x[((b*CC + c)*TT + t)*LL + l];

  const float* Ws[3] = {Wq, Wk, Wv};
  const float* bs[3] = {bq, bk, bv};
  float* ds[3] = {qo, ko, vo};
  #pragma unroll
  for (int p = 0; p < 3; ++p) {
    const float* W = Ws[p];
    const float* bi = bs[p];
    float* dst = ds[p];
    const float post = (p == 0) ? 0.5f : 1.0f;   // fold 1/sqrt(D) into q
    #pragma unroll
    for (int h = 0; h < HH; ++h) {
      float yv[DD];
      #pragma unroll
      for (int d = 0; d < DD; ++d) {
        int co = h*DD + d;
        float acc = bi[co];
        #pragma unroll
        for (int ci = 0; ci < CC; ++ci) acc += xv[ci] * W[co*CC + ci];
        yv[d] = acc;
      }
      float n = sqrtf(yv[0]*yv[0] + yv[1]*yv[1] + yv[2]*yv[2] + yv[3]*yv[3]);
      float inv = post / fmaxf(n, 1e-12f);
      float4 o4 = make_float4(yv[0]*inv, yv[1]*inv, yv[2]*inv, yv[3]*inv);
      *reinterpret_cast<float4*>(&dst[(bt*HH + h)*(LL*DD) + l*DD]) = o4;
    }
  }
}

// ---------------- fused attention ----------------
// grid (72, 16), block 512.  wave handles rows iblk*32 + wave*4 + r; lane owns j = lane + jj*64.
// K staged in LDS (64 KB -> 2 blocks/CU); V read from global (L1/L2-resident, coalesced).
__global__ __launch_bounds__(512, 4) void attn_kernel(
    const float* __restrict__ q, const float* __restrict__ k, const float* __restrict__ v,
    const float* __restrict__ Wl, const float* __restrict__ Wc,
    const float* __restrict__ mb, float* __restrict__ xatt) {
  __shared__ float k_lds[HH*LL*DD];   // 64 KB

  const int bt   = blockIdx.x;
  const int iblk = blockIdx.y;
  const int tid  = threadIdx.x;
  const int wave = __builtin_amdgcn_readfirstlane(tid >> 6);   // uniform
  const int lane = tid & 63;

  {
    const float* kg = k + (size_t)bt*(HH*LL*DD);
    #pragma unroll
    for (int it = 0; it < 8; ++it) {
      int idx = (it*512 + tid) * 4;
      *reinterpret_cast<float4*>(&k_lds[idx]) = *reinterpret_cast<const float4*>(&kg[idx]);
    }
  }
  __syncthreads();

  const float* vg = v + (size_t)bt*(HH*LL*DD);

  for (int r = 0; r < 4; ++r) {
    const int i = iblk*32 + wave*4 + r;    // uniform per wave

    // ---- init logits with mixed rel-pos bias
    float lg[HH][8];
    #pragma unroll
    for (int Ho = 0; Ho < HH; ++Ho) {
      const float* mrow = mb + Ho*RELN + i + (LL-1);
      #pragma unroll
      for (int jj = 0; jj < 8; ++jj)
        lg[Ho][jj] = mrow[-(lane + jj*64)];
    }

    // ---- q row (uniform address -> scalar loads)
    const float* qrow = q + (size_t)(bt*HH)*(LL*DD) + i*DD;
    float4 qv[HH];
    #pragma unroll
    for (int h = 0; h < HH; ++h)
      qv[h] = *reinterpret_cast<const float4*>(&qrow[h*(LL*DD)]);

    // ---- scores (per jj, transient s[8]) + head-mix 1 (Wl from SGPR-cached global)
    #pragma unroll
    for (int jj = 0; jj < 8; ++jj) {
      int j = lane + jj*64;
      float s[HH];
      #pragma unroll
      for (int h = 0; h < HH; ++h) {
        float4 kv = *reinterpret_cast<const float4*>(&k_lds[(h*LL + j)*DD]);
        s[h] = qv[h].x*kv.x + qv[h].y*kv.y + qv[h].z*kv.z + qv[h].w*kv.w;
      }
      #pragma unroll
      for (int h = 0; h < HH; ++h)
        #pragma unroll
        for (int Ho = 0; Ho < HH; ++Ho)
          lg[Ho][jj] += s[h] * Wl[h*HH + Ho];
    }

    // ---- softmax over 512 j per output head; |logits| <= ~0.7 so no max-subtraction
    #pragma unroll
    for (int Ho = 0; Ho < HH; ++Ho) {
      float ssum = 0.f;
      #pragma unroll
      for (int jj = 0; jj < 8; ++jj) {
        float e = __expf(lg[Ho][jj]);
        lg[Ho][jj] = e;
        ssum += e;
      }
      #pragma unroll
      for (int off = 32; off >= 1; off >>= 1) ssum += __shfl_xor(ssum, off);
      float inv = 1.0f / ssum;
      #pragma unroll
      for (int jj = 0; jj < 8; ++jj) lg[Ho][jj] *= inv;
    }

    // ---- head-mix 2 + PV, streamed per output head (a[8]+o[4] transient)
    #pragma unroll
    for (int Ho = 0; Ho < HH; ++Ho) {
      float a[8];
      #pragma unroll
      for (int jj = 0; jj < 8; ++jj) a[jj] = lg[0][jj] * Wc[Ho];
      #pragma unroll
      for (int h = 1; h < HH; ++h)
        #pragma unroll
        for (int jj = 0; jj < 8; ++jj) a[jj] += lg[h][jj] * Wc[h*HH + Ho];

      float ox = 0.f, oy = 0.f, oz = 0.f, ow = 0.f;
      const float* vrow = vg + (size_t)Ho*(LL*DD);
      #pragma unroll
      for (int jj = 0; jj < 8; ++jj) {
        int j = lane + jj*64;
        float4 vv = *reinterpret_cast<const float4*>(&vrow[j*DD]);
        ox += a[jj]*vv.x; oy += a[jj]*vv.y; oz += a[jj]*vv.z; ow += a[jj]*vv.w;
      }
      #pragma unroll
      for (int off = 32; off >= 1; off >>= 1) {
        ox += __shfl_xor(ox, off); oy += __shfl_xor(oy, off);
        oz += __shfl_xor(oz, off); ow += __shfl_xor(ow, off);
      }
      if (lane == 0)
        *reinterpret_cast<float4*>(&xatt[((size_t)bt*LL + i)*CC + Ho*DD]) =
            make_float4(ox, oy, oz, ow);
    }
  }
}

// ---------------- Wm projection; t<8 -> final out, t==8 -> xm8 scratch ----------------
__global__ __launch_bounds__(256) void wm_kernel(
    const float* __restrict__ xatt, const float* __restrict__ Wm, const float* __restrict__ bm,
    float* __restrict__ out, float* __restrict__ xm8) {
  int g = blockIdx.x * 256 + threadIdx.x;
  int l  = g & (LL-1);
  int bt = g >> 9;
  int b = bt / TT, t = bt - b*TT;
  float xv[CC];
  #pragma unroll
  for (int c = 0; c < CC; c += 4) {
    float4 x4 = *reinterpret_cast<const float4*>(&xatt[g*CC + c]);
    xv[c] = x4.x; xv[c+1] = x4.y; xv[c+2] = x4.z; xv[c+3] = x4.w;
  }
  #pragma unroll
  for (int co = 0; co < CC; ++co) {
    float acc = bm[co];
    #pragma unroll
    for (int ci = 0; ci < CC; ++ci) acc += xv[ci] * Wm[co*CC + ci];
    if (t < TT-1) out[((b*CC + co)*TT + t)*LL + l] = acc;
    else          xm8[(b*CC + co)*LL + l] = acc;
  }
}

// ---------------- conv over (ci,t) + BN(eval) + ReLU ----------------
__global__ __launch_bounds__(512) void conv_kernel(
    const float* __restrict__ out, const float* __restrict__ pp,
    const float* __restrict__ cw, const float* __restrict__ cb,
    const float* __restrict__ bng, const float* __restrict__ bnb,
    float* __restrict__ yws) {
  int bc = blockIdx.x;            // b*32 + co
  int b = bc >> 5, co = bc & 31;
  int l = threadIdx.x;
  float acc = cb[co];
  #pragma unroll
  for (int ci = 0; ci < CC; ++ci) {
    const float* base = out + ((b*CC + ci)*TT)*LL + l;
    const float* w = cw + (co*CC + ci)*TT;
    #pragma unroll
    for (int t = 0; t < TT-1; ++t) acc += base[t*LL] * w[t];
    acc += pp[ci*LL + l] * w[TT-1];
  }
  float scale = bng[co] * 0.999995000037499687f;   // 1/sqrt(1+1e-5)
  float val = acc * scale + bnb[co];
  yws[bc*LL + l] = fmaxf(val, 0.f);
}

// ---------------- token-linear p = y @ pl_w.T + pl_b; out[t=8] = xm8 - p ----------------
__global__ __launch_bounds__(512) void pl_kernel(
    const float* __restrict__ yws, const float* __restrict__ plwT,
    const float* __restrict__ plb, const float* __restrict__ xm8,
    float* __restrict__ out) {
  __shared__ float sy[2][LL];
  int bc0 = blockIdx.x * 2;
  int tid = threadIdx.x;
  sy[0][tid] = yws[bc0*LL + tid];
  sy[1][tid] = yws[(bc0+1)*LL + tid];
  __syncthreads();
  float acc0 = plb[tid], acc1 = plb[tid];
  #pragma unroll 4
  for (int l = 0; l < LL; ++l) {
    float w = plwT[l*LL + tid];
    acc0 += sy[0][l] * w;
    acc1 += sy[1][l] * w;
  }
  out[(bc0*TT + (TT-1))*LL + tid]       = xm8[bc0*LL + tid] - acc0;
  out[((bc0+1)*TT + (TT-1))*LL + tid]   = xm8[(bc0+1)*LL + tid] - acc1;
}

extern "C" void kernel_launch(void* const* d_in, const int* in_sizes, int n_in,
                              void* d_out, int out_size, void* d_ws, size_t ws_size,
                              hipStream_t stream) {
  const float* x    = (const float*)d_in[0];
  const float* Wq   = (const float*)d_in[1];
  const float* bq   = (const float*)d_in[2];
  const float* Wk   = (const float*)d_in[3];
  const float* bk   = (const float*)d_in[4];
  const float* Wv   = (const float*)d_in[5];
  const float* bv   = (const float*)d_in[6];
  const float* Wm   = (const float*)d_in[7];
  const float* bm   = (const float*)d_in[8];
  const float* Wl   = (const float*)d_in[9];
  const float* Wc   = (const float*)d_in[10];
  const float* rpb  = (const float*)d_in[11];
  const float* pp   = (const float*)d_in[12];
  const float* cw   = (const float*)d_in[13];
  const float* cb   = (const float*)d_in[14];
  const float* bng  = (const float*)d_in[15];
  const float* bnb  = (const float*)d_in[16];
  const float* plw  = (const float*)d_in[17];
  const float* plb  = (const float*)d_in[18];
  float* out = (float*)d_out;

  float* ws = (float*)d_ws;
  const size_t QKV = (size_t)NBT*HH*LL*DD;     // 1179648
  float* q_ws   = ws;                 // QKV
  float* k_ws   = q_ws + QKV;         // QKV
  float* v_ws   = k_ws + QKV;         // QKV
  float* xatt   = v_ws + QKV;         // NBT*LL*CC = 1179648
  float* xm8    = xatt + QKV;         // BB*CC*LL = 131072
  float* yws    = xm8 + (size_t)BB*CC*LL;      // 131072
  float* plwT   = yws + (size_t)BB*CC*LL;      // 262144
  float* mbias  = plwT + (size_t)LL*LL;        // 8184

  mixed_bias_kernel<<<2, 512, 0, stream>>>(rpb, Wl, mbias);
  transpose512_kernel<<<dim3(16,16), 256, 0, stream>>>(plw, plwT);
  proj_kernel<<<(BB*TT*LL)/256, 256, 0, stream>>>(x, Wq, bq, Wk, bk, Wv, bv, q_ws, k_ws, v_ws);
  attn_kernel<<<dim3(NBT, 16), 512, 0, stream>>>(q_ws, k_ws, v_ws, Wl, Wc, mbias, xatt);
  wm_kernel<<<(BB*TT*LL)/256, 256, 0, stream>>>(xatt, Wm, bm, out, xm8);
  conv_kernel<<<BB*CC, LL, 0, stream>>>(out, pp, cw, cb, bng, bnb, yws);
  pl_kernel<<<(BB*CC)/2, LL, 0, stream>>>(yws, plwT, plb, xm8, out);
}

// Round 3
// 1205.363 us; speedup vs baseline: 1.7843x; 1.7843x over previous
//
#include <hip/hip_runtime.h>
#include <math.h>

#define BB 8
#define CC 32
#define TT 9
#define LL 512
#define HH 8
#define DD 4
#define NBT (BB*TT)          // 72
#define RELN (2*LL-1)        // 1023

// ---------------- mixed bias: mb[Ho][idx] = sum_h rpb[h][idx] * Wl[h][Ho] ----------------
__global__ void mixed_bias_kernel(const float* __restrict__ rpb,
                                  const float* __restrict__ Wl,
                                  float* __restrict__ mb) {
  int idx = blockIdx.x * blockDim.x + threadIdx.x;
  if (idx >= RELN) return;
  float r[HH];
  #pragma unroll
  for (int h = 0; h < HH; ++h) r[h] = rpb[h*RELN + idx];
  #pragma unroll
  for (int Ho = 0; Ho < HH; ++Ho) {
    float acc = 0.f;
    #pragma unroll
    for (int h = 0; h < HH; ++h) acc += r[h] * Wl[h*HH + Ho];
    mb[Ho*RELN + idx] = acc;
  }
}

// ---------------- transpose pl_w (512x512): outT[l][l'] = in[l'][l] ----------------
__global__ __launch_bounds__(256) void transpose512_kernel(const float* __restrict__ in,
                                                           float* __restrict__ outT) {
  __shared__ float tile[32][33];
  int bx = blockIdx.x * 32, by = blockIdx.y * 32;
  int tx = threadIdx.x & 31, ty = threadIdx.x >> 5;   // 32x8
  #pragma unroll
  for (int yy = ty; yy < 32; yy += 8)
    tile[yy][tx] = in[(by + yy)*LL + bx + tx];
  __syncthreads();
  #pragma unroll
  for (int yy = ty; yy < 32; yy += 8)
    outT[(bx + yy)*LL + by + tx] = tile[tx][yy];
}

// ---------------- q/k/v projection + l2norm (q additionally scaled by 1/sqrt(D)=0.5) ----
// out layout: dst[(bt*HH + h)*(LL*DD) + l*DD + d]
__global__ __launch_bounds__(256) void proj_kernel(
    const float* __restrict__ x,
    const float* __restrict__ Wq, const float* __restrict__ bq,
    const float* __restrict__ Wk, const float* __restrict__ bk,
    const float* __restrict__ Wv, const float* __restrict__ bv,
    float* __restrict__ qo, float* __restrict__ ko, float* __restrict__ vo) {
  int g = blockIdx.x * 256 + threadIdx.x;    // 0..36863
  int l  = g & (LL-1);
  int bt = g >> 9;
  int b = bt / TT, t = bt - b*TT;

  float xv[CC];
  #pragma unroll
  for (int c = 0; c < CC; ++c)
    xv[c] = x[((b*CC + c)*TT + t)*LL + l];

  const float* Ws[3] = {Wq, Wk, Wv};
  const float* bs[3] = {bq, bk, bv};
  float* ds[3] = {qo, ko, vo};
  #pragma unroll
  for (int p = 0; p < 3; ++p) {
    const float* W = Ws[p];
    const float* bi = bs[p];
    float* dst = ds[p];
    const float post = (p == 0) ? 0.5f : 1.0f;   // fold 1/sqrt(D) into q
    #pragma unroll
    for (int h = 0; h < HH; ++h) {
      float yv[DD];
      #pragma unroll
      for (int d = 0; d < DD; ++d) {
        int co = h*DD + d;
        float acc = bi[co];
        #pragma unroll
        for (int ci = 0; ci < CC; ++ci) acc += xv[ci] * W[co*CC + ci];
        yv[d] = acc;
      }
      float n = sqrtf(yv[0]*yv[0] + yv[1]*yv[1] + yv[2]*yv[2] + yv[3]*yv[3]);
      float inv = post / fmaxf(n, 1e-12f);
      float4 o4 = make_float4(yv[0]*inv, yv[1]*inv, yv[2]*inv, yv[3]*inv);
      *reinterpret_cast<float4*>(&dst[(bt*HH + h)*(LL*DD) + l*DD]) = o4;
    }
  }
}

// ---------------- fused attention ----------------
// 1D grid of 72*32=2304 blocks, 256 threads (4 waves). XCD-chunked swizzle so each
// XCD owns 9 consecutive bt (V re-reads stay L2-resident). Wave handles 4 rows.
// K staged in LDS (64 KB -> 2 blocks/CU); V read from global (L1/L2-resident).
// launch_bounds (256,2): VGPR cap 256 -> NO scratch spill (live state ~130 regs).
__global__ __launch_bounds__(256, 2) void attn_kernel(
    const float* __restrict__ q, const float* __restrict__ k, const float* __restrict__ v,
    const float* __restrict__ Wl, const float* __restrict__ Wc,
    const float* __restrict__ mb, float* __restrict__ xatt) {
  __shared__ float k_lds[HH*LL*DD];   // 64 KB

  // XCD swizzle: 2304 blocks, 8 XCDs, 288 per XCD (2304 % 8 == 0 -> bijective)
  const int wgid = blockIdx.x;
  const int id   = (wgid & 7) * 288 + (wgid >> 3);
  const int bt   = id >> 5;     // id / 32
  const int iblk = id & 31;     // id % 32

  const int tid  = threadIdx.x;
  const int wave = __builtin_amdgcn_readfirstlane(tid >> 6);   // uniform
  const int lane = tid & 63;

  {
    const float* kg = k + (size_t)bt*(HH*LL*DD);
    #pragma unroll
    for (int it = 0; it < 16; ++it) {
      int idx = (it*256 + tid) * 4;
      *reinterpret_cast<float4*>(&k_lds[idx]) = *reinterpret_cast<const float4*>(&kg[idx]);
    }
  }
  __syncthreads();

  const float* vg = v + (size_t)bt*(HH*LL*DD);

  for (int r = 0; r < 4; ++r) {
    const int i = iblk*16 + wave*4 + r;    // uniform per wave

    // ---- init logits with mixed rel-pos bias
    float lg[HH][8];
    #pragma unroll
    for (int Ho = 0; Ho < HH; ++Ho) {
      const float* mrow = mb + Ho*RELN + i + (LL-1);
      #pragma unroll
      for (int jj = 0; jj < 8; ++jj)
        lg[Ho][jj] = mrow[-(lane + jj*64)];
    }

    // ---- q row (uniform address -> broadcast loads)
    const float* qrow = q + (size_t)(bt*HH)*(LL*DD) + i*DD;
    float4 qv[HH];
    #pragma unroll
    for (int h = 0; h < HH; ++h)
      qv[h] = *reinterpret_cast<const float4*>(&qrow[h*(LL*DD)]);

    // ---- scores (per jj, transient s[8]) + head-mix 1
    #pragma unroll
    for (int jj = 0; jj < 8; ++jj) {
      int j = lane + jj*64;
      float s[HH];
      #pragma unroll
      for (int h = 0; h < HH; ++h) {
        float4 kv = *reinterpret_cast<const float4*>(&k_lds[(h*LL + j)*DD]);
        s[h] = qv[h].x*kv.x + qv[h].y*kv.y + qv[h].z*kv.z + qv[h].w*kv.w;
      }
      #pragma unroll
      for (int h = 0; h < HH; ++h)
        #pragma unroll
        for (int Ho = 0; Ho < HH; ++Ho)
          lg[Ho][jj] += s[h] * Wl[h*HH + Ho];
    }

    // ---- softmax over 512 j per output head; |logits| <= ~0.7 so no max-subtraction
    #pragma unroll
    for (int Ho = 0; Ho < HH; ++Ho) {
      float ssum = 0.f;
      #pragma unroll
      for (int jj = 0; jj < 8; ++jj) {
        float e = __expf(lg[Ho][jj]);
        lg[Ho][jj] = e;
        ssum += e;
      }
      #pragma unroll
      for (int off = 32; off >= 1; off >>= 1) ssum += __shfl_xor(ssum, off);
      float inv = 1.0f / ssum;
      #pragma unroll
      for (int jj = 0; jj < 8; ++jj) lg[Ho][jj] *= inv;
    }

    // ---- head-mix 2 + PV, streamed per output head (a[8]+o[4] transient)
    #pragma unroll
    for (int Ho = 0; Ho < HH; ++Ho) {
      float a[8];
      #pragma unroll
      for (int jj = 0; jj < 8; ++jj) a[jj] = lg[0][jj] * Wc[Ho];
      #pragma unroll
      for (int h = 1; h < HH; ++h)
        #pragma unroll
        for (int jj = 0; jj < 8; ++jj) a[jj] += lg[h][jj] * Wc[h*HH + Ho];

      float ox = 0.f, oy = 0.f, oz = 0.f, ow = 0.f;
      const float* vrow = vg + (size_t)Ho*(LL*DD);
      #pragma unroll
      for (int jj = 0; jj < 8; ++jj) {
        int j = lane + jj*64;
        float4 vv = *reinterpret_cast<const float4*>(&vrow[j*DD]);
        ox += a[jj]*vv.x; oy += a[jj]*vv.y; oz += a[jj]*vv.z; ow += a[jj]*vv.w;
      }
      #pragma unroll
      for (int off = 32; off >= 1; off >>= 1) {
        ox += __shfl_xor(ox, off); oy += __shfl_xor(oy, off);
        oz += __shfl_xor(oz, off); ow += __shfl_xor(ow, off);
      }
      if (lane == 0)
        *reinterpret_cast<float4*>(&xatt[((size_t)bt*LL + i)*CC + Ho*DD]) =
            make_float4(ox, oy, oz, ow);
    }
  }
}

// ---------------- Wm projection; t<8 -> final out, t==8 -> xm8 scratch ----------------
__global__ __launch_bounds__(256) void wm_kernel(
    const float* __restrict__ xatt, const float* __restrict__ Wm, const float* __restrict__ bm,
    float* __restrict__ out, float* __restrict__ xm8) {
  int g = blockIdx.x * 256 + threadIdx.x;
  int l  = g & (LL-1);
  int bt = g >> 9;
  int b = bt / TT, t = bt - b*TT;
  float xv[CC];
  #pragma unroll
  for (int c = 0; c < CC; c += 4) {
    float4 x4 = *reinterpret_cast<const float4*>(&xatt[g*CC + c]);
    xv[c] = x4.x; xv[c+1] = x4.y; xv[c+2] = x4.z; xv[c+3] = x4.w;
  }
  #pragma unroll
  for (int co = 0; co < CC; ++co) {
    float acc = bm[co];
    #pragma unroll
    for (int ci = 0; ci < CC; ++ci) acc += xv[ci] * Wm[co*CC + ci];
    if (t < TT-1) out[((b*CC + co)*TT + t)*LL + l] = acc;
    else          xm8[(b*CC + co)*LL + l] = acc;
  }
}

// ---------------- conv over (ci,t) + BN(eval) + ReLU ----------------
__global__ __launch_bounds__(512) void conv_kernel(
    const float* __restrict__ out, const float* __restrict__ pp,
    const float* __restrict__ cw, const float* __restrict__ cb,
    const float* __restrict__ bng, const float* __restrict__ bnb,
    float* __restrict__ yws) {
  int bc = blockIdx.x;            // b*32 + co
  int b = bc >> 5, co = bc & 31;
  int l = threadIdx.x;
  float acc = cb[co];
  #pragma unroll
  for (int ci = 0; ci < CC; ++ci) {
    const float* base = out + ((b*CC + ci)*TT)*LL + l;
    const float* w = cw + (co*CC + ci)*TT;
    #pragma unroll
    for (int t = 0; t < TT-1; ++t) acc += base[t*LL] * w[t];
    acc += pp[ci*LL + l] * w[TT-1];
  }
  float scale = bng[co] * 0.999995000037499687f;   // 1/sqrt(1+1e-5)
  float val = acc * scale + bnb[co];
  yws[bc*LL + l] = fmaxf(val, 0.f);
}

// ---------------- token-linear p = y @ pl_w.T + pl_b; out[t=8] = xm8 - p ----------------
__global__ __launch_bounds__(512) void pl_kernel(
    const float* __restrict__ yws, const float* __restrict__ plwT,
    const float* __restrict__ plb, const float* __restrict__ xm8,
    float* __restrict__ out) {
  __shared__ float sy[2][LL];
  int bc0 = blockIdx.x * 2;
  int tid = threadIdx.x;
  sy[0][tid] = yws[bc0*LL + tid];
  sy[1][tid] = yws[(bc0+1)*LL + tid];
  __syncthreads();
  float acc0 = plb[tid], acc1 = plb[tid];
  #pragma unroll 4
  for (int l = 0; l < LL; ++l) {
    float w = plwT[l*LL + tid];
    acc0 += sy[0][l] * w;
    acc1 += sy[1][l] * w;
  }
  out[(bc0*TT + (TT-1))*LL + tid]       = xm8[bc0*LL + tid] - acc0;
  out[((bc0+1)*TT + (TT-1))*LL + tid]   = xm8[(bc0+1)*LL + tid] - acc1;
}

extern "C" void kernel_launch(void* const* d_in, const int* in_sizes, int n_in,
                              void* d_out, int out_size, void* d_ws, size_t ws_size,
                              hipStream_t stream) {
  const float* x    = (const float*)d_in[0];
  const float* Wq   = (const float*)d_in[1];
  const float* bq   = (const float*)d_in[2];
  const float* Wk   = (const float*)d_in[3];
  const float* bk   = (const float*)d_in[4];
  const float* Wv   = (const float*)d_in[5];
  const float* bv   = (const float*)d_in[6];
  const float* Wm   = (const float*)d_in[7];
  const float* bm   = (const float*)d_in[8];
  const float* Wl   = (const float*)d_in[9];
  const float* Wc   = (const float*)d_in[10];
  const float* rpb  = (const float*)d_in[11];
  const float* pp   = (const float*)d_in[12];
  const float* cw   = (const float*)d_in[13];
  const float* cb   = (const float*)d_in[14];
  const float* bng  = (const float*)d_in[15];
  const float* bnb  = (const float*)d_in[16];
  const float* plw  = (const float*)d_in[17];
  const float* plb  = (const float*)d_in[18];
  float* out = (float*)d_out;

  float* ws = (float*)d_ws;
  const size_t QKV = (size_t)NBT*HH*LL*DD;     // 1179648
  float* q_ws   = ws;                 // QKV
  float* k_ws   = q_ws + QKV;         // QKV
  float* v_ws   = k_ws + QKV;         // QKV
  float* xatt   = v_ws + QKV;         // NBT*LL*CC = 1179648
  float* xm8    = xatt + QKV;         // BB*CC*LL = 131072
  float* yws    = xm8 + (size_t)BB*CC*LL;      // 131072
  float* plwT   = yws + (size_t)BB*CC*LL;      // 262144
  float* mbias  = plwT + (size_t)LL*LL;        // 8184

  mixed_bias_kernel<<<2, 512, 0, stream>>>(rpb, Wl, mbias);
  transpose512_kernel<<<dim3(16,16), 256, 0, stream>>>(plw, plwT);
  proj_kernel<<<(BB*TT*LL)/256, 256, 0, stream>>>(x, Wq, bq, Wk, bk, Wv, bv, q_ws, k_ws, v_ws);
  attn_kernel<<<NBT*32, 256, 0, stream>>>(q_ws, k_ws, v_ws, Wl, Wc, mbias, xatt);
  wm_kernel<<<(BB*TT*LL)/256, 256, 0, stream>>>(xatt, Wm, bm, out, xm8);
  conv_kernel<<<BB*CC, LL, 0, stream>>>(out, pp, cw, cb, bng, bnb, yws);
  pl_kernel<<<(BB*CC)/2, LL, 0, stream>>>(yws, plwT, plb, xm8, out);
}

// Round 4
// 382.239 us; speedup vs baseline: 5.6267x; 3.1534x over previous
//
#include <hip/hip_runtime.h>
#include <math.h>

#define BB 8
#define CC 32
#define TT 9
#define LL 512
#define HH 8
#define DD 4
#define NBT (BB*TT)          // 72
#define RELN (2*LL-1)        // 1023

// ---------------- mixed bias: mb[Ho][idx] = sum_h rpb[h][idx] * Wl[h][Ho] ----------------
__global__ void mixed_bias_kernel(const float* __restrict__ rpb,
                                  const float* __restrict__ Wl,
                                  float* __restrict__ mb) {
  int idx = blockIdx.x * blockDim.x + threadIdx.x;
  if (idx >= RELN) return;
  float r[HH];
  #pragma unroll
  for (int h = 0; h < HH; ++h) r[h] = rpb[h*RELN + idx];
  #pragma unroll
  for (int Ho = 0; Ho < HH; ++Ho) {
    float acc = 0.f;
    #pragma unroll
    for (int h = 0; h < HH; ++h) acc += r[h] * Wl[h*HH + Ho];
    mb[Ho*RELN + idx] = acc;
  }
}

// ---------------- transpose pl_w (512x512): outT[l][l'] = in[l'][l] ----------------
__global__ __launch_bounds__(256) void transpose512_kernel(const float* __restrict__ in,
                                                           float* __restrict__ outT) {
  __shared__ float tile[32][33];
  int bx = blockIdx.x * 32, by = blockIdx.y * 32;
  int tx = threadIdx.x & 31, ty = threadIdx.x >> 5;   // 32x8
  #pragma unroll
  for (int yy = ty; yy < 32; yy += 8)
    tile[yy][tx] = in[(by + yy)*LL + bx + tx];
  __syncthreads();
  #pragma unroll
  for (int yy = ty; yy < 32; yy += 8)
    outT[(bx + yy)*LL + by + tx] = tile[tx][yy];
}

// ---------------- q/k/v projection + l2norm (q additionally scaled by 1/sqrt(D)=0.5) ----
// out layout: dst[(bt*HH + h)*(LL*DD) + l*DD + d]
__global__ __launch_bounds__(256) void proj_kernel(
    const float* __restrict__ x,
    const float* __restrict__ Wq, const float* __restrict__ bq,
    const float* __restrict__ Wk, const float* __restrict__ bk,
    const float* __restrict__ Wv, const float* __restrict__ bv,
    float* __restrict__ qo, float* __restrict__ ko, float* __restrict__ vo) {
  int g = blockIdx.x * 256 + threadIdx.x;    // 0..36863
  int l  = g & (LL-1);
  int bt = g >> 9;
  int b = bt / TT, t = bt - b*TT;

  float xv[CC];
  #pragma unroll
  for (int c = 0; c < CC; ++c)
    xv[c] = x[((b*CC + c)*TT + t)*LL + l];

  const float* Ws[3] = {Wq, Wk, Wv};
  const float* bs[3] = {bq, bk, bv};
  float* ds[3] = {qo, ko, vo};
  #pragma unroll
  for (int p = 0; p < 3; ++p) {
    const float* W = Ws[p];
    const float* bi = bs[p];
    float* dst = ds[p];
    const float post = (p == 0) ? 0.5f : 1.0f;   // fold 1/sqrt(D) into q
    #pragma unroll
    for (int h = 0; h < HH; ++h) {
      float yv[DD];
      #pragma unroll
      for (int d = 0; d < DD; ++d) {
        int co = h*DD + d;
        float acc = bi[co];
        #pragma unroll
        for (int ci = 0; ci < CC; ++ci) acc += xv[ci] * W[co*CC + ci];
        yv[d] = acc;
      }
      float n = sqrtf(yv[0]*yv[0] + yv[1]*yv[1] + yv[2]*yv[2] + yv[3]*yv[3]);
      float inv = post / fmaxf(n, 1e-12f);
      float4 o4 = make_float4(yv[0]*inv, yv[1]*inv, yv[2]*inv, yv[3]*inv);
      *reinterpret_cast<float4*>(&dst[(bt*HH + h)*(LL*DD) + l*DD]) = o4;
    }
  }
}

// ---------------- fused attention (v3: 2 waves per row, no spill) ----------------
// 2304 blocks x 256 thr (4 waves = 2 wave-pairs). Each pair processes 8 rows; within a
// row, wave-half f owns j in [f*256, f*256+256), each lane 4 j's -> lg[8][4]=32 regs.
// Peak live ~85 VGPR -> fits 128 with NO scratch. K in LDS (64 KB -> 2 blocks/CU),
// V from global (L2-resident via XCD-chunked swizzle). Cross-wave reduces via 1 KB LDS.
__global__ __launch_bounds__(256, 2) void attn_kernel(
    const float* __restrict__ q, const float* __restrict__ k, const float* __restrict__ v,
    const float* __restrict__ Wl, const float* __restrict__ Wc,
    const float* __restrict__ mb, float* __restrict__ xatt) {
  __shared__ float k_lds[HH*LL*DD];     // 64 KB
  __shared__ float red[4][HH];          // per-wave softmax partial sums
  __shared__ float opart[4][CC];        // per-wave PV partials (elem = Ho*4+d)

  // XCD swizzle: 2304 blocks, 8 XCDs, 288 per XCD (2304 % 8 == 0 -> bijective)
  const int wgid = blockIdx.x;
  const int id   = (wgid & 7) * 288 + (wgid >> 3);
  const int bt   = id >> 5;     // [0,72)
  const int iblk = id & 31;     // [0,32)

  const int tid  = threadIdx.x;
  const int wave = __builtin_amdgcn_readfirstlane(tid >> 6);   // uniform
  const int lane = tid & 63;
  const int pair = wave >> 1;   // 0,1
  const int half = wave & 1;    // 0,1

  {
    const float* kg = k + (size_t)bt*(HH*LL*DD);
    #pragma unroll
    for (int it = 0; it < 16; ++it) {
      int idx = (it*256 + tid) * 4;
      *reinterpret_cast<float4*>(&k_lds[idx]) = *reinterpret_cast<const float4*>(&kg[idx]);
    }
  }
  __syncthreads();

  const float* vg = v + (size_t)bt*(HH*LL*DD);
  const int jbase = half*256 + lane;    // j = jbase + jj*64, jj=0..3

  for (int rr = 0; rr < 8; ++rr) {
    const int i = iblk*16 + pair*8 + rr;    // uniform per wave

    // ---- init logits with mixed rel-pos bias
    float lg[HH][4];
    #pragma unroll
    for (int Ho = 0; Ho < HH; ++Ho) {
      const float* mrow = mb + Ho*RELN + (i + (LL-1) - jbase);
      #pragma unroll
      for (int jj = 0; jj < 4; ++jj)
        lg[Ho][jj] = mrow[-(jj*64)];
    }

    // ---- scores + head-mix 1 (qv live only in this scope)
    {
      const float* qrow = q + (size_t)(bt*HH)*(LL*DD) + i*DD;
      float4 qv[HH];
      #pragma unroll
      for (int h = 0; h < HH; ++h)
        qv[h] = *reinterpret_cast<const float4*>(&qrow[h*(LL*DD)]);
      #pragma unroll
      for (int jj = 0; jj < 4; ++jj) {
        int j = jbase + jj*64;
        float s[HH];
        #pragma unroll
        for (int h = 0; h < HH; ++h) {
          float4 kv = *reinterpret_cast<const float4*>(&k_lds[(h*LL + j)*DD]);
          s[h] = qv[h].x*kv.x + qv[h].y*kv.y + qv[h].z*kv.z + qv[h].w*kv.w;
        }
        #pragma unroll
        for (int h = 0; h < HH; ++h)
          #pragma unroll
          for (int Ho = 0; Ho < HH; ++Ho)
            lg[Ho][jj] += s[h] * Wl[h*HH + Ho];
      }
    }

    // ---- exp + per-wave sums (|logits| small: no max-subtraction needed)
    float ssum[HH];
    #pragma unroll
    for (int Ho = 0; Ho < HH; ++Ho) {
      float e0 = __expf(lg[Ho][0]), e1 = __expf(lg[Ho][1]);
      float e2 = __expf(lg[Ho][2]), e3 = __expf(lg[Ho][3]);
      lg[Ho][0] = e0; lg[Ho][1] = e1; lg[Ho][2] = e2; lg[Ho][3] = e3;
      float s01 = e0 + e1, s23 = e2 + e3;
      float t = s01 + s23;
      #pragma unroll
      for (int off = 32; off >= 1; off >>= 1) t += __shfl_xor(t, off);
      ssum[Ho] = t;   // all lanes hold the wave-partial sum
    }
    if (lane == 0) {
      *reinterpret_cast<float4*>(&red[wave][0]) = make_float4(ssum[0], ssum[1], ssum[2], ssum[3]);
      *reinterpret_cast<float4*>(&red[wave][4]) = make_float4(ssum[4], ssum[5], ssum[6], ssum[7]);
    }
    __syncthreads();
    {
      const int pw = wave ^ 1;
      #pragma unroll
      for (int m = 0; m < HH; ++m) {
        float inv = 1.0f / (ssum[m] + red[pw][m]);
        #pragma unroll
        for (int jj = 0; jj < 4; ++jj) lg[m][jj] *= inv;
      }
    }

    // ---- head-mix 2 + PV into acc[Ho*4+d]
    float acc[CC];
    #pragma unroll
    for (int e = 0; e < CC; ++e) acc[e] = 0.f;
    #pragma unroll
    for (int Ho = 0; Ho < HH; ++Ho) {
      float a[4];
      #pragma unroll
      for (int jj = 0; jj < 4; ++jj) a[jj] = lg[0][jj] * Wc[Ho];
      #pragma unroll
      for (int m = 1; m < HH; ++m)
        #pragma unroll
        for (int jj = 0; jj < 4; ++jj) a[jj] += lg[m][jj] * Wc[m*HH + Ho];
      const float* vrow = vg + (size_t)Ho*(LL*DD);
      #pragma unroll
      for (int jj = 0; jj < 4; ++jj) {
        float4 vv = *reinterpret_cast<const float4*>(&vrow[(jbase + jj*64)*DD]);
        acc[Ho*4+0] += a[jj]*vv.x; acc[Ho*4+1] += a[jj]*vv.y;
        acc[Ho*4+2] += a[jj]*vv.z; acc[Ho*4+3] += a[jj]*vv.w;
      }
    }

    // ---- fold reduction: 32 values over 64 lanes (exchange-and-halve)
    #pragma unroll
    for (int t = 0; t < 16; ++t) {
      float send = (lane & 1) ? acc[t] : acc[16 + t];
      float recv = __shfl_xor(send, 1);
      float keep = (lane & 1) ? acc[16 + t] : acc[t];
      acc[t] = keep + recv;
    }
    #pragma unroll
    for (int t = 0; t < 8; ++t) {
      float send = (lane & 2) ? acc[t] : acc[8 + t];
      float recv = __shfl_xor(send, 2);
      float keep = (lane & 2) ? acc[8 + t] : acc[t];
      acc[t] = keep + recv;
    }
    #pragma unroll
    for (int t = 0; t < 4; ++t) {
      float send = (lane & 4) ? acc[t] : acc[4 + t];
      float recv = __shfl_xor(send, 4);
      float keep = (lane & 4) ? acc[4 + t] : acc[t];
      acc[t] = keep + recv;
    }
    #pragma unroll
    for (int t = 0; t < 2; ++t) {
      float send = (lane & 8) ? acc[t] : acc[2 + t];
      float recv = __shfl_xor(send, 8);
      float keep = (lane & 8) ? acc[2 + t] : acc[t];
      acc[t] = keep + recv;
    }
    {
      float send = (lane & 16) ? acc[0] : acc[1];
      float recv = __shfl_xor(send, 16);
      float keep = (lane & 16) ? acc[1] : acc[0];
      acc[0] = keep + recv;
    }
    acc[0] += __shfl_xor(acc[0], 32);
    // lane (for lane<32) holds element e = bitrev5(lane) of the 32-vector
    if (lane < 32) {
      int e = ((lane & 1) << 4) | ((lane & 2) << 2) | (lane & 4) |
              ((lane & 8) >> 2) | ((lane & 16) >> 4);
      opart[wave][e] = acc[0];
    }
    __syncthreads();
    if (half == 0 && lane < 32) {
      float r0 = opart[wave][lane] + opart[wave + 1][lane];
      xatt[((size_t)bt*LL + i)*CC + lane] = r0;
    }
  }
}

// ---------------- Wm projection; t<8 -> final out, t==8 -> xm8 scratch ----------------
__global__ __launch_bounds__(256) void wm_kernel(
    const float* __restrict__ xatt, const float* __restrict__ Wm, const float* __restrict__ bm,
    float* __restrict__ out, float* __restrict__ xm8) {
  int g = blockIdx.x * 256 + threadIdx.x;
  int l  = g & (LL-1);
  int bt = g >> 9;
  int b = bt / TT, t = bt - b*TT;
  float xv[CC];
  #pragma unroll
  for (int c = 0; c < CC; c += 4) {
    float4 x4 = *reinterpret_cast<const float4*>(&xatt[g*CC + c]);
    xv[c] = x4.x; xv[c+1] = x4.y; xv[c+2] = x4.z; xv[c+3] = x4.w;
  }
  #pragma unroll
  for (int co = 0; co < CC; ++co) {
    float acc = bm[co];
    #pragma unroll
    for (int ci = 0; ci < CC; ++ci) acc += xv[ci] * Wm[co*CC + ci];
    if (t < TT-1) out[((b*CC + co)*TT + t)*LL + l] = acc;
    else          xm8[(b*CC + co)*LL + l] = acc;
  }
}

// ---------------- conv over (ci,t) + BN(eval) + ReLU ----------------
__global__ __launch_bounds__(512) void conv_kernel(
    const float* __restrict__ out, const float* __restrict__ pp,
    const float* __restrict__ cw, const float* __restrict__ cb,
    const float* __restrict__ bng, const float* __restrict__ bnb,
    float* __restrict__ yws) {
  int bc = blockIdx.x;            // b*32 + co
  int b = bc >> 5, co = bc & 31;
  int l = threadIdx.x;
  float acc = cb[co];
  #pragma unroll
  for (int ci = 0; ci < CC; ++ci) {
    const float* base = out + ((b*CC + ci)*TT)*LL + l;
    const float* w = cw + (co*CC + ci)*TT;
    #pragma unroll
    for (int t = 0; t < TT-1; ++t) acc += base[t*LL] * w[t];
    acc += pp[ci*LL + l] * w[TT-1];
  }
  float scale = bng[co] * 0.999995000037499687f;   // 1/sqrt(1+1e-5)
  float val = acc * scale + bnb[co];
  yws[bc*LL + l] = fmaxf(val, 0.f);
}

// ---------------- token-linear p = y @ pl_w.T + pl_b; out[t=8] = xm8 - p ----------------
__global__ __launch_bounds__(512) void pl_kernel(
    const float* __restrict__ yws, const float* __restrict__ plwT,
    const float* __restrict__ plb, const float* __restrict__ xm8,
    float* __restrict__ out) {
  __shared__ float sy[2][LL];
  int bc0 = blockIdx.x * 2;
  int tid = threadIdx.x;
  sy[0][tid] = yws[bc0*LL + tid];
  sy[1][tid] = yws[(bc0+1)*LL + tid];
  __syncthreads();
  float acc0 = plb[tid], acc1 = plb[tid];
  #pragma unroll 4
  for (int l = 0; l < LL; ++l) {
    float w = plwT[l*LL + tid];
    acc0 += sy[0][l] * w;
    acc1 += sy[1][l] * w;
  }
  out[(bc0*TT + (TT-1))*LL + tid]       = xm8[bc0*LL + tid] - acc0;
  out[((bc0+1)*TT + (TT-1))*LL + tid]   = xm8[(bc0+1)*LL + tid] - acc1;
}

extern "C" void kernel_launch(void* const* d_in, const int* in_sizes, int n_in,
                              void* d_out, int out_size, void* d_ws, size_t ws_size,
                              hipStream_t stream) {
  const float* x    = (const float*)d_in[0];
  const float* Wq   = (const float*)d_in[1];
  const float* bq   = (const float*)d_in[2];
  const float* Wk   = (const float*)d_in[3];
  const float* bk   = (const float*)d_in[4];
  const float* Wv   = (const float*)d_in[5];
  const float* bv   = (const float*)d_in[6];
  const float* Wm   = (const float*)d_in[7];
  const float* bm   = (const float*)d_in[8];
  const float* Wl   = (const float*)d_in[9];
  const float* Wc   = (const float*)d_in[10];
  const float* rpb  = (const float*)d_in[11];
  const float* pp   = (const float*)d_in[12];
  const float* cw   = (const float*)d_in[13];
  const float* cb   = (const float*)d_in[14];
  const float* bng  = (const float*)d_in[15];
  const float* bnb  = (const float*)d_in[16];
  const float* plw  = (const float*)d_in[17];
  const float* plb  = (const float*)d_in[18];
  float* out = (float*)d_out;

  float* ws = (float*)d_ws;
  const size_t QKV = (size_t)NBT*HH*LL*DD;     // 1179648
  float* q_ws   = ws;                 // QKV
  float* k_ws   = q_ws + QKV;         // QKV
  float* v_ws   = k_ws + QKV;         // QKV
  float* xatt   = v_ws + QKV;         // NBT*LL*CC = 1179648
  float* xm8    = xatt + QKV;         // BB*CC*LL = 131072
  float* yws    = xm8 + (size_t)BB*CC*LL;      // 131072
  float* plwT   = yws + (size_t)BB*CC*LL;      // 262144
  float* mbias  = plwT + (size_t)LL*LL;        // 8184

  mixed_bias_kernel<<<2, 512, 0, stream>>>(rpb, Wl, mbias);
  transpose512_kernel<<<dim3(16,16), 256, 0, stream>>>(plw, plwT);
  proj_kernel<<<(BB*TT*LL)/256, 256, 0, stream>>>(x, Wq, bq, Wk, bk, Wv, bv, q_ws, k_ws, v_ws);
  attn_kernel<<<NBT*32, 256, 0, stream>>>(q_ws, k_ws, v_ws, Wl, Wc, mbias, xatt);
  wm_kernel<<<(BB*TT*LL)/256, 256, 0, stream>>>(xatt, Wm, bm, out, xm8);
  conv_kernel<<<BB*CC, LL, 0, stream>>>(out, pp, cw, cb, bng, bnb, yws);
  pl_kernel<<<(BB*CC)/2, LL, 0, stream>>>(yws, plwT, plb, xm8, out);
}

// Round 5
// 373.099 us; speedup vs baseline: 5.7646x; 1.0245x over previous
//
#include <hip/hip_runtime.h>
#include <math.h>

#define BB 8
#define CC 32
#define TT 9
#define LL 512
#define HH 8
#define DD 4
#define NBT (BB*TT)          // 72
#define RELN (2*LL-1)        // 1023

typedef float v2f __attribute__((ext_vector_type(2)));

// ---------------- mixed bias: mb[Ho][idx] = sum_h rpb[h][idx] * Wl[h][Ho] ----------------
__global__ void mixed_bias_kernel(const float* __restrict__ rpb,
                                  const float* __restrict__ Wl,
                                  float* __restrict__ mb) {
  int idx = blockIdx.x * blockDim.x + threadIdx.x;
  if (idx >= RELN) return;
  float r[HH];
  #pragma unroll
  for (int h = 0; h < HH; ++h) r[h] = rpb[h*RELN + idx];
  #pragma unroll
  for (int Ho = 0; Ho < HH; ++Ho) {
    float acc = 0.f;
    #pragma unroll
    for (int h = 0; h < HH; ++h) acc += r[h] * Wl[h*HH + Ho];
    mb[Ho*RELN + idx] = acc;
  }
}

// ---------------- transpose pl_w (512x512): outT[l][l'] = in[l'][l] ----------------
__global__ __launch_bounds__(256) void transpose512_kernel(const float* __restrict__ in,
                                                           float* __restrict__ outT) {
  __shared__ float tile[32][33];
  int bx = blockIdx.x * 32, by = blockIdx.y * 32;
  int tx = threadIdx.x & 31, ty = threadIdx.x >> 5;   // 32x8
  #pragma unroll
  for (int yy = ty; yy < 32; yy += 8)
    tile[yy][tx] = in[(by + yy)*LL + bx + tx];
  __syncthreads();
  #pragma unroll
  for (int yy = ty; yy < 32; yy += 8)
    outT[(bx + yy)*LL + by + tx] = tile[tx][yy];
}

// ---------------- q/k/v projection + l2norm (q additionally scaled by 1/sqrt(D)=0.5) ----
// out layout: dst[(bt*HH + h)*(LL*DD) + l*DD + d]
__global__ __launch_bounds__(256) void proj_kernel(
    const float* __restrict__ x,
    const float* __restrict__ Wq, const float* __restrict__ bq,
    const float* __restrict__ Wk, const float* __restrict__ bk,
    const float* __restrict__ Wv, const float* __restrict__ bv,
    float* __restrict__ qo, float* __restrict__ ko, float* __restrict__ vo) {
  int g = blockIdx.x * 256 + threadIdx.x;    // 0..36863
  int l  = g & (LL-1);
  int bt = g >> 9;
  int b = bt / TT, t = bt - b*TT;

  float xv[CC];
  #pragma unroll
  for (int c = 0; c < CC; ++c)
    xv[c] = x[((b*CC + c)*TT + t)*LL + l];

  const float* Ws[3] = {Wq, Wk, Wv};
  const float* bs[3] = {bq, bk, bv};
  float* ds[3] = {qo, ko, vo};
  #pragma unroll
  for (int p = 0; p < 3; ++p) {
    const float* W = Ws[p];
    const float* bi = bs[p];
    float* dst = ds[p];
    const float post = (p == 0) ? 0.5f : 1.0f;   // fold 1/sqrt(D) into q
    #pragma unroll
    for (int h = 0; h < HH; ++h) {
      float yv[DD];
      #pragma unroll
      for (int d = 0; d < DD; ++d) {
        int co = h*DD + d;
        float acc = bi[co];
        #pragma unroll
        for (int ci = 0; ci < CC; ++ci) acc += xv[ci] * W[co*CC + ci];
        yv[d] = acc;
      }
      float n = sqrtf(yv[0]*yv[0] + yv[1]*yv[1] + yv[2]*yv[2] + yv[3]*yv[3]);
      float inv = post / fmaxf(n, 1e-12f);
      float4 o4 = make_float4(yv[0]*inv, yv[1]*inv, yv[2]*inv, yv[3]*inv);
      *reinterpret_cast<float4*>(&dst[(bt*HH + h)*(LL*DD) + l*DD]) = o4;
    }
  }
}

// ---------------- fused attention (v4: 512 thr/block = 16 waves/CU, float2-packed) ----
// 1152 blocks x 512 thr (8 waves = 4 pairs). Pair handles 8 rows; halves split j-space.
// Each lane: 4 j's as 2x v2f. K in LDS (64 KB, 2 blocks/CU -> 16 waves/CU). V from
// global (L2-resident via XCD swizzle). Hot FMA loops in float2 for v_pk_fma_f32.
#define ACC(e) acc2[(e)>>1][(e)&1]
__global__ __launch_bounds__(512, 2) void attn_kernel(
    const float* __restrict__ q, const float* __restrict__ k, const float* __restrict__ v,
    const float* __restrict__ Wl, const float* __restrict__ Wc,
    const float* __restrict__ mb, float* __restrict__ xatt) {
  __shared__ float k_lds[HH*LL*DD];     // 64 KB
  __shared__ float red[8][HH];          // per-wave softmax partial sums
  __shared__ float opart[8][CC];        // per-wave PV partials (elem = Ho*4+d)

  // XCD swizzle: 1152 blocks, 8 XCDs, 144 per XCD (1152 % 8 == 0 -> bijective)
  const int wgid = blockIdx.x;
  const int id   = (wgid & 7) * 144 + (wgid >> 3);
  const int bt   = id >> 4;     // [0,72)
  const int iblk = id & 15;     // [0,16)

  const int tid  = threadIdx.x;
  const int wave = __builtin_amdgcn_readfirstlane(tid >> 6);   // uniform
  const int lane = tid & 63;
  const int pair = wave >> 1;   // 0..3
  const int half = wave & 1;    // 0,1

  {
    const float* kg = k + (size_t)bt*(HH*LL*DD);
    #pragma unroll
    for (int it = 0; it < 8; ++it) {
      int idx = (it*512 + tid) * 4;
      *reinterpret_cast<float4*>(&k_lds[idx]) = *reinterpret_cast<const float4*>(&kg[idx]);
    }
  }
  __syncthreads();

  const float* vg = v + (size_t)bt*(HH*LL*DD);
  const int jbase = half*256 + lane;    // j = jbase + jj*64, jj=0..3

  for (int rr = 0; rr < 8; ++rr) {
    const int i = iblk*32 + pair*8 + rr;    // uniform per wave

    // ---- init logits with mixed rel-pos bias: lg2[Ho][p] = jj{2p,2p+1}
    v2f lg2[HH][2];
    #pragma unroll
    for (int Ho = 0; Ho < HH; ++Ho) {
      const float* mrow = mb + Ho*RELN + (i + (LL-1) - jbase);
      lg2[Ho][0][0] = mrow[0];
      lg2[Ho][0][1] = mrow[-64];
      lg2[Ho][1][0] = mrow[-128];
      lg2[Ho][1][1] = mrow[-192];
    }

    // ---- scores + head-mix 1 (qv live only in this scope)
    {
      const float* qrow = q + (size_t)(bt*HH)*(LL*DD) + i*DD;
      float4 qv[HH];
      #pragma unroll
      for (int h = 0; h < HH; ++h)
        qv[h] = *reinterpret_cast<const float4*>(&qrow[h*(LL*DD)]);
      #pragma unroll
      for (int p = 0; p < 2; ++p) {
        const int j0 = jbase + (2*p)*64;
        v2f s2[HH];
        #pragma unroll
        for (int h = 0; h < HH; ++h) {
          float4 k0 = *reinterpret_cast<const float4*>(&k_lds[(h*LL + j0)*DD]);
          float4 k1 = *reinterpret_cast<const float4*>(&k_lds[(h*LL + j0 + 64)*DD]);
          s2[h][0] = qv[h].x*k0.x + qv[h].y*k0.y + qv[h].z*k0.z + qv[h].w*k0.w;
          s2[h][1] = qv[h].x*k1.x + qv[h].y*k1.y + qv[h].z*k1.z + qv[h].w*k1.w;
        }
        #pragma unroll
        for (int h = 0; h < HH; ++h) {
          #pragma unroll
          for (int Ho = 0; Ho < HH; ++Ho) {
            float w = Wl[h*HH + Ho];
            lg2[Ho][p] += s2[h] * (v2f){w, w};
          }
        }
      }
    }

    // ---- exp + per-wave sums (|logits| small: no max-subtraction needed)
    float ssum[HH];
    #pragma unroll
    for (int Ho = 0; Ho < HH; ++Ho) {
      float e0 = __expf(lg2[Ho][0][0]), e1 = __expf(lg2[Ho][0][1]);
      float e2 = __expf(lg2[Ho][1][0]), e3 = __expf(lg2[Ho][1][1]);
      lg2[Ho][0][0] = e0; lg2[Ho][0][1] = e1; lg2[Ho][1][0] = e2; lg2[Ho][1][1] = e3;
      float t = (e0 + e1) + (e2 + e3);
      #pragma unroll
      for (int off = 32; off >= 1; off >>= 1) t += __shfl_xor(t, off);
      ssum[Ho] = t;   // all lanes hold the wave-partial sum
    }
    if (lane == 0) {
      *reinterpret_cast<float4*>(&red[wave][0]) = make_float4(ssum[0], ssum[1], ssum[2], ssum[3]);
      *reinterpret_cast<float4*>(&red[wave][4]) = make_float4(ssum[4], ssum[5], ssum[6], ssum[7]);
    }
    __syncthreads();
    {
      const int pw = wave ^ 1;
      #pragma unroll
      for (int m = 0; m < HH; ++m) {
        float inv = __builtin_amdgcn_rcpf(ssum[m] + red[pw][m]);
        lg2[m][0] *= (v2f){inv, inv};
        lg2[m][1] *= (v2f){inv, inv};
      }
    }

    // ---- head-mix 2 + PV into acc2 (elem e = Ho*4+d at acc2[e>>1][e&1])
    v2f acc2[16];
    #pragma unroll
    for (int e = 0; e < 16; ++e) acc2[e] = (v2f){0.f, 0.f};
    #pragma unroll
    for (int Ho = 0; Ho < HH; ++Ho) {
      v2f a2[2];
      {
        float w = Wc[Ho];
        a2[0] = lg2[0][0] * (v2f){w, w};
        a2[1] = lg2[0][1] * (v2f){w, w};
      }
      #pragma unroll
      for (int m = 1; m < HH; ++m) {
        float w = Wc[m*HH + Ho];
        a2[0] += lg2[m][0] * (v2f){w, w};
        a2[1] += lg2[m][1] * (v2f){w, w};
      }
      const float* vrow = vg + (size_t)Ho*(LL*DD);
      #pragma unroll
      for (int jj = 0; jj < 4; ++jj) {
        float a = a2[jj >> 1][jj & 1];
        float4 vv = *reinterpret_cast<const float4*>(&vrow[(jbase + jj*64)*DD]);
        acc2[Ho*2 + 0] += (v2f){a, a} * (v2f){vv.x, vv.y};
        acc2[Ho*2 + 1] += (v2f){a, a} * (v2f){vv.z, vv.w};
      }
    }

    // ---- fold reduction: 32 values over 64 lanes (exchange-and-halve)
    #pragma unroll
    for (int t = 0; t < 16; ++t) {
      float send = (lane & 1) ? ACC(t) : ACC(16 + t);
      float recv = __shfl_xor(send, 1);
      float keep = (lane & 1) ? ACC(16 + t) : ACC(t);
      ACC(t) = keep + recv;
    }
    #pragma unroll
    for (int t = 0; t < 8; ++t) {
      float send = (lane & 2) ? ACC(t) : ACC(8 + t);
      float recv = __shfl_xor(send, 2);
      float keep = (lane & 2) ? ACC(8 + t) : ACC(t);
      ACC(t) = keep + recv;
    }
    #pragma unroll
    for (int t = 0; t < 4; ++t) {
      float send = (lane & 4) ? ACC(t) : ACC(4 + t);
      float recv = __shfl_xor(send, 4);
      float keep = (lane & 4) ? ACC(4 + t) : ACC(t);
      ACC(t) = keep + recv;
    }
    #pragma unroll
    for (int t = 0; t < 2; ++t) {
      float send = (lane & 8) ? ACC(t) : ACC(2 + t);
      float recv = __shfl_xor(send, 8);
      float keep = (lane & 8) ? ACC(2 + t) : ACC(t);
      ACC(t) = keep + recv;
    }
    {
      float send = (lane & 16) ? ACC(0) : ACC(1);
      float recv = __shfl_xor(send, 16);
      float keep = (lane & 16) ? ACC(1) : ACC(0);
      ACC(0) = keep + recv;
    }
    ACC(0) += __shfl_xor(ACC(0), 32);
    // lane (for lane<32) holds element e = bitrev5(lane) of the 32-vector
    if (lane < 32) {
      int e = ((lane & 1) << 4) | ((lane & 2) << 2) | (lane & 4) |
              ((lane & 8) >> 2) | ((lane & 16) >> 4);
      opart[wave][e] = ACC(0);
    }
    __syncthreads();
    if (half == 0 && lane < 32) {
      float r0 = opart[wave][lane] + opart[wave + 1][lane];
      xatt[((size_t)bt*LL + i)*CC + lane] = r0;
    }
  }
}

// ---------------- Wm projection; t<8 -> final out, t==8 -> xm8 scratch ----------------
__global__ __launch_bounds__(256) void wm_kernel(
    const float* __restrict__ xatt, const float* __restrict__ Wm, const float* __restrict__ bm,
    float* __restrict__ out, float* __restrict__ xm8) {
  int g = blockIdx.x * 256 + threadIdx.x;
  int l  = g & (LL-1);
  int bt = g >> 9;
  int b = bt / TT, t = bt - b*TT;
  float xv[CC];
  #pragma unroll
  for (int c = 0; c < CC; c += 4) {
    float4 x4 = *reinterpret_cast<const float4*>(&xatt[g*CC + c]);
    xv[c] = x4.x; xv[c+1] = x4.y; xv[c+2] = x4.z; xv[c+3] = x4.w;
  }
  #pragma unroll
  for (int co = 0; co < CC; ++co) {
    float acc = bm[co];
    #pragma unroll
    for (int ci = 0; ci < CC; ++ci) acc += xv[ci] * Wm[co*CC + ci];
    if (t < TT-1) out[((b*CC + co)*TT + t)*LL + l] = acc;
    else          xm8[(b*CC + co)*LL + l] = acc;
  }
}

// ---------------- conv over (ci,t) + BN(eval) + ReLU ----------------
__global__ __launch_bounds__(512) void conv_kernel(
    const float* __restrict__ out, const float* __restrict__ pp,
    const float* __restrict__ cw, const float* __restrict__ cb,
    const float* __restrict__ bng, const float* __restrict__ bnb,
    float* __restrict__ yws) {
  int bc = blockIdx.x;            // b*32 + co
  int b = bc >> 5, co = bc & 31;
  int l = threadIdx.x;
  float acc = cb[co];
  #pragma unroll
  for (int ci = 0; ci < CC; ++ci) {
    const float* base = out + ((b*CC + ci)*TT)*LL + l;
    const float* w = cw + (co*CC + ci)*TT;
    #pragma unroll
    for (int t = 0; t < TT-1; ++t) acc += base[t*LL] * w[t];
    acc += pp[ci*LL + l] * w[TT-1];
  }
  float scale = bng[co] * 0.999995000037499687f;   // 1/sqrt(1+1e-5)
  float val = acc * scale + bnb[co];
  yws[bc*LL + l] = fmaxf(val, 0.f);
}

// ---------------- token-linear p = y @ pl_w.T + pl_b; out[t=8] = xm8 - p ----------------
__global__ __launch_bounds__(512) void pl_kernel(
    const float* __restrict__ yws, const float* __restrict__ plwT,
    const float* __restrict__ plb, const float* __restrict__ xm8,
    float* __restrict__ out) {
  __shared__ float sy[2][LL];
  int bc0 = blockIdx.x * 2;
  int tid = threadIdx.x;
  sy[0][tid] = yws[bc0*LL + tid];
  sy[1][tid] = yws[(bc0+1)*LL + tid];
  __syncthreads();
  float acc0 = plb[tid], acc1 = plb[tid];
  #pragma unroll 4
  for (int l = 0; l < LL; ++l) {
    float w = plwT[l*LL + tid];
    acc0 += sy[0][l] * w;
    acc1 += sy[1][l] * w;
  }
  out[(bc0*TT + (TT-1))*LL + tid]       = xm8[bc0*LL + tid] - acc0;
  out[((bc0+1)*TT + (TT-1))*LL + tid]   = xm8[(bc0+1)*LL + tid] - acc1;
}

extern "C" void kernel_launch(void* const* d_in, const int* in_sizes, int n_in,
                              void* d_out, int out_size, void* d_ws, size_t ws_size,
                              hipStream_t stream) {
  const float* x    = (const float*)d_in[0];
  const float* Wq   = (const float*)d_in[1];
  const float* bq   = (const float*)d_in[2];
  const float* Wk   = (const float*)d_in[3];
  const float* bk   = (const float*)d_in[4];
  const float* Wv   = (const float*)d_in[5];
  const float* bv   = (const float*)d_in[6];
  const float* Wm   = (const float*)d_in[7];
  const float* bm   = (const float*)d_in[8];
  const float* Wl   = (const float*)d_in[9];
  const float* Wc   = (const float*)d_in[10];
  const float* rpb  = (const float*)d_in[11];
  const float* pp   = (const float*)d_in[12];
  const float* cw   = (const float*)d_in[13];
  const float* cb   = (const float*)d_in[14];
  const float* bng  = (const float*)d_in[15];
  const float* bnb  = (const float*)d_in[16];
  const float* plw  = (const float*)d_in[17];
  const float* plb  = (const float*)d_in[18];
  float* out = (float*)d_out;

  float* ws = (float*)d_ws;
  const size_t QKV = (size_t)NBT*HH*LL*DD;     // 1179648
  float* q_ws   = ws;                 // QKV
  float* k_ws   = q_ws + QKV;         // QKV
  float* v_ws   = k_ws + QKV;         // QKV
  float* xatt   = v_ws + QKV;         // NBT*LL*CC = 1179648
  float* xm8    = xatt + QKV;         // BB*CC*LL = 131072
  float* yws    = xm8 + (size_t)BB*CC*LL;      // 131072
  float* plwT   = yws + (size_t)BB*CC*LL;      // 262144
  float* mbias  = plwT + (size_t)LL*LL;        // 8184

  mixed_bias_kernel<<<2, 512, 0, stream>>>(rpb, Wl, mbias);
  transpose512_kernel<<<dim3(16,16), 256, 0, stream>>>(plw, plwT);
  proj_kernel<<<(BB*TT*LL)/256, 256, 0, stream>>>(x, Wq, bq, Wk, bk, Wv, bv, q_ws, k_ws, v_ws);
  attn_kernel<<<NBT*16, 512, 0, stream>>>(q_ws, k_ws, v_ws, Wl, Wc, mbias, xatt);
  wm_kernel<<<(BB*TT*LL)/256, 256, 0, stream>>>(xatt, Wm, bm, out, xm8);
  conv_kernel<<<BB*CC, LL, 0, stream>>>(out, pp, cw, cb, bng, bnb, yws);
  pl_kernel<<<(BB*CC)/2, LL, 0, stream>>>(yws, plwT, plb, xm8, out);
}